// Round 16
// baseline (452.021 us; speedup 1.0000x reference)
//
#include <hip/hip_runtime.h>
#include <math.h>

#define NTOK   16384
#define DDIM   256
#define HWD    1024        // H*W per batch image
#define CHW    262144      // 256*1024 floats per batch
#define MARGIN 3.0e-4f     // i8 stat (8+ sigma of est-diff) + ref d-grid + fp16 quant
#define CLIPF  5.5f
#define QS     (127.0f/5.5f)
#define EQS    2080768.0f  // 16384*127
#define SCALE  (5.5f/(127.0f*127.0f*16384.0f))   // sz*se

// ws layout (bytes)
#define WS_TI8   0u          // 4 MB  i8 token images [128 tiles][4 chunks][128 rows][64B swz]
#define WS_CI8   4194304u    // 4 MB  i8 code rows PLAIN [code][256]
#define WS_M3    8388608u    // 16 MB fp16 min-d_est per 32-code group: [n][512]
#define WS_FLG   25165824u   // 16KB per-token clip flags
#define WS_EE    25182208u   // 64KB
#define WS_ZZ    25247744u   // 64KB
#define WS_IDX   25313280u   // 64KB
#define WS_CNT   25378816u   // 64KB
#define WS_LSUM  25444352u   // 16KB per-block loss partials [2048] fp64

typedef __attribute__((ext_vector_type(4)))  int   i32x4;
typedef __attribute__((ext_vector_type(16))) char  c16;
typedef __attribute__((ext_vector_type(8)))  _Float16 h8f;
typedef unsigned long long ull;

// ---------------- fused prep: blocks 0..255 tokens, 256..511 codes ----------------
__global__ __launch_bounds__(256) void k_prep(const float* __restrict__ z,
                                              const float* __restrict__ emb,
                                              char* __restrict__ Ti8,
                                              char* __restrict__ Ci8,
                                              float* __restrict__ zz,
                                              float* __restrict__ ee,
                                              float* __restrict__ zt,
                                              unsigned char* __restrict__ flags) {
  const int bid = blockIdx.x;
  const int tid = threadIdx.x;
  const int t64 = tid & 63, chunk = tid >> 6;
  if (bid < 256) {                      // ---- token role
    __shared__ double part[4][64];
    __shared__ int   fpart[4][64];
    const int n = bid * 64 + t64;
    const int b = n >> 10, hw = n & 1023;
    const float* zp = z + (size_t)b * CHW + hw;
    float tmp[64];
    double s = 0.0;
    int clip = 0;
    #pragma unroll
    for (int j = 0; j < 64; ++j) {      // coalesced across t64 for each j
      const float f = zp[(size_t)(chunk * 64 + j) * HWD];
      tmp[j] = f;
      s += (double)f * (double)f;
      clip |= (fabsf(f) > CLIPF) ? 1 : 0;
    }
    c16 q[4];
    #pragma unroll
    for (int sl = 0; sl < 4; ++sl)
      #pragma unroll
      for (int j = 0; j < 16; ++j)
        q[sl][j] = (char)(int)rintf(fminf(fmaxf(tmp[sl * 16 + j], -CLIPF), CLIPF) * QS);
    const int rl = n & 127, tile = n >> 7;
    char* dst = Ti8 + (size_t)tile * 32768 + chunk * 8192 + rl * 64;
    const int sw = ((rl >> 1) & 3) << 4;
    #pragma unroll
    for (int sl = 0; sl < 4; ++sl) *(c16*)(dst + ((sl * 16) ^ sw)) = q[sl];
    float* ztp = zt + (size_t)n * 256 + chunk * 64;
    #pragma unroll
    for (int j4 = 0; j4 < 16; ++j4) *(float4*)(ztp + j4 * 4) = *(float4*)&tmp[j4 * 4];
    part[chunk][t64] = s;
    fpart[chunk][t64] = clip;
    __syncthreads();
    if (tid < 64) {
      zz[n] = (float)(part[0][t64] + part[1][t64] + part[2][t64] + part[3][t64]);
      flags[n] = (unsigned char)(fpart[0][t64] | fpart[1][t64] | fpart[2][t64] | fpart[3][t64]);
    }
  } else {                              // ---- code role (coalesced via LDS transpose)
    __shared__ float rows[64][257];     // +1 pad
    __shared__ double part2[4][64];
    const int k0 = (bid - 256) * 64;
    for (int i = tid; i < 16384; i += 256)
      rows[i >> 8][i & 255] = emb[(size_t)k0 * DDIM + i];
    __syncthreads();
    const int code = k0 + t64;
    double s = 0.0;
    c16 q[4];
    #pragma unroll
    for (int sl = 0; sl < 4; ++sl)
      #pragma unroll
      for (int j = 0; j < 16; ++j) {
        const float f = rows[t64][chunk * 64 + sl * 16 + j];
        q[sl][j] = (char)(int)rintf(f * EQS);   // range-safe (|e|<=1/16384 -> |q|<=127)
        s += (double)f * (double)f;
      }
    char* dst = Ci8 + (size_t)code * 256 + chunk * 64;   // PLAIN layout
    #pragma unroll
    for (int sl = 0; sl < 4; ++sl) *(c16*)(dst + sl * 16) = q[sl];
    part2[chunk][t64] = s;
    __syncthreads();
    if (tid < 64)
      ee[code] = (float)(part2[0][t64] + part2[1][t64] + part2[2][t64] + part2[3][t64]);
  }
}

// ---------------- phase-1: i8 GEMM (R13 geometry), 32-code-group-min epilogue ----------------
// grid 2048 = 8 XCD x 16 ctile-local x 16 ttile-groups; 256 thr = 4 waves (2 code x 2 token).
// Block: ctile (128 codes, A-frags in VGPR) x 8 ttiles of 128 tokens (B dbuf in LDS).
// Epilogue: per (token, 32-code group) min of d_est: 14 max + 4 shfl per n (vs top-2's ~90).
// Group gid = ctile*4 + wr*2 + g covers codes gid*32..+32.
__global__ __launch_bounds__(256) void k_mdist(
    const char* __restrict__ tokimg, const char* __restrict__ codrows,
    _Float16* __restrict__ M3) {
  __shared__ __attribute__((aligned(16))) char ldsB[65536];   // 2 x 32KB token tiles
  __shared__ _Float16 m3l[2][512];
  const int raw = blockIdx.x;
  const int p = raw & 7;                        // XCD
  const int ctile = p * 16 + ((raw >> 3) & 15); // 0..127
  const int tgrp = raw >> 7;                    // 0..15 (8 ttiles each)
  const int tid = threadIdx.x;
  const int w = tid >> 6, lane = tid & 63;
  const int wr = w >> 1, wc = w & 1;            // code-half, token-half
  const int fr = lane & 15, fq = lane >> 4;

  // A-frags: 64 codes x K=256 in VGPRs, loaded once from plain rows
  i32x4 afr[4][4];                              // [m][kc]
  {
    const char* ab = codrows + (size_t)(ctile * 128 + wr * 64 + fr) * 256 + fq * 16;
    #pragma unroll
    for (int m = 0; m < 4; ++m)
      #pragma unroll
      for (int kc = 0; kc < 4; ++kc)
        afr[m][kc] = *(const i32x4*)(ab + m * 16 * 256 + kc * 64);
  }

  int boff[4][4];                               // [n][kc] LDS offsets (swizzled image)
  #pragma unroll
  for (int n = 0; n < 4; ++n)
    #pragma unroll
    for (int kc = 0; kc < 4; ++kc) {
      const int t = wc * 64 + n * 16 + fr;
      boff[n][kc] = kc * 8192 + t * 64 + ((fq * 16) ^ (((t >> 1) & 3) << 4));
    }

  #define STAGEB(buf, tt)                                                             \
    {                                                                                 \
      const char* src = tokimg + (size_t)(tt) * 32768;                                \
      char* dstb = ldsB + (buf) * 32768;                                              \
      _Pragma("unroll")                                                               \
      for (int r = 0; r < 8; ++r) {                                                   \
        const int u = r * 256 + tid;                                                  \
        __builtin_amdgcn_global_load_lds(                                             \
            (const __attribute__((address_space(1))) void*)(src + u * 16),            \
            (__attribute__((address_space(3))) void*)(dstb + u * 16), 16, 0, 0);      \
      }                                                                               \
    }

  STAGEB(0, tgrp * 8);
  __syncthreads();                              // buf0 ready

  for (int it = 0; it < 8; ++it) {
    const int pb = it & 1;
    const int ttile = tgrp * 8 + it;
    if (it < 7) STAGEB(pb ^ 1, ttile + 1);      // prefetch next B
    const char* bufb = ldsB + pb * 32768;

    i32x4 acc[4][4];
    #pragma unroll
    for (int m = 0; m < 4; ++m)
      #pragma unroll
      for (int n = 0; n < 4; ++n) acc[m][n] = (i32x4)0;

    __builtin_amdgcn_s_setprio(1);
    #pragma unroll
    for (int kc = 0; kc < 4; ++kc) {
      i32x4 b[4];
      #pragma unroll
      for (int n = 0; n < 4; ++n) b[n] = *(const i32x4*)(bufb + boff[n][kc]);
      #pragma unroll
      for (int m = 0; m < 4; ++m)
        #pragma unroll
        for (int n = 0; n < 4; ++n)
          acc[m][n] = __builtin_amdgcn_mfma_i32_16x16x64_i8(afr[m][kc], b[n], acc[m][n], 0, 0, 0);
    }
    __builtin_amdgcn_s_setprio(0);

    // group-min epilogue: per (token fr+n*16, 32-code group g = m-pair)
    #pragma unroll
    for (int n = 0; n < 4; ++n) {
      #pragma unroll
      for (int g = 0; g < 2; ++g) {
        int v = max(max(acc[2 * g][n][0], acc[2 * g][n][1]),
                    max(acc[2 * g][n][2], acc[2 * g][n][3]));
        v = max(v, max(max(acc[2 * g + 1][n][0], acc[2 * g + 1][n][1]),
                       max(acc[2 * g + 1][n][2], acc[2 * g + 1][n][3])));
        v = max(v, __shfl_xor(v, 16, 64));
        v = max(v, __shfl_xor(v, 32, 64));      // max over the 32 codes of group
        if (lane < 16)
          m3l[pb][(wc * 64 + n * 16 + fr) * 4 + wr * 2 + g] =
              (_Float16)(-2.0f * SCALE * (float)v);
      }
    }
    __syncthreads();                    // fences m3l[pb] + drains stage(it+1)
    if (tid < 128) {
      const int tok = ttile * 128 + tid;
      *(ull*)(M3 + (size_t)tok * 512 + ctile * 4) = *(const ull*)(&m3l[pb][tid * 4]);
    }
    // no trailing barrier: m3l double-buffered (safe per next iter's barrier ordering)
  }
}

// ---------------- phase-2: wave-per-token; group-filter + 16-wide exact fp64 argmin ----------------
// grid 2048 x 256 thr = 4 waves; each wave owns 2 tokens end-to-end. Candidate 32-code
// groups come straight from M3 (no per-code reduces); their codes get the exact fp64
// recheck at 16 codes/pass (4 lanes/code, 2 width-4 shfls). Winner's group always passes.
__global__ __launch_bounds__(256) void k_pick(
    const float* __restrict__ zt, const float* __restrict__ emb,
    const float* __restrict__ zz, const float* __restrict__ ee,
    const _Float16* __restrict__ M3, const unsigned char* __restrict__ flags,
    int* __restrict__ idx, float* __restrict__ out_idxf,
    int* __restrict__ counts, double* __restrict__ lsum) {
  __shared__ float zrow[4][260];        // per-wave z row
  __shared__ int   glist[4][32];        // per-wave candidate groups
  __shared__ int   gcnt[4];
  __shared__ double wsum[4];
  const int tid = threadIdx.x;
  const int w = tid >> 6, lane = tid & 63;
  const int c16p = lane >> 2, l4 = lane & 3;
  double dsum = 0.0;
  for (int ni = 0; ni < 2; ++ni) {
    const int n = blockIdx.x * 8 + w * 2 + ni;
    if (lane == 0) gcnt[w] = 0;
    // z row: 64 lanes x float4 (coalesced 1KB)
    *(float4*)&zrow[w][lane * 4] = *(const float4*)(zt + (size_t)n * 256 + lane * 4);
    // M3 row scan: lane covers groups lane*8..+7 (one coalesced 16B load)
    const h8f mv = *(const h8f*)(M3 + (size_t)n * 512 + lane * 8);
    float t8[8];
    #pragma unroll
    for (int s = 0; s < 8; ++s) t8[s] = (float)mv[s];
    float mr = t8[0];
    #pragma unroll
    for (int s = 1; s < 8; ++s) mr = fminf(mr, t8[s]);
    #pragma unroll
    for (int o = 32; o; o >>= 1) mr = fminf(mr, __shfl_xor(mr, o, 64));
    const int ex0 = flags[n];
    const float thr = ex0 ? 3.0e38f : mr + MARGIN;
    if (!ex0) {
      #pragma unroll
      for (int s = 0; s < 8; ++s) {
        if (t8[s] <= thr) {
          const int pos = atomicAdd(&gcnt[w], 1);
          if (pos < 32) glist[w][pos] = lane * 8 + s;
        }
      }
    }
    const int ng = gcnt[w];             // same-wave DS order: pushes visible
    const int doEx = ex0 || (ng > 32);
    const int nchunk = doEx ? 1024 : ng * 2;    // 16-code chunks
    const float zzn = zz[n];
    ull best = ~0ull;
    const float* zp4 = &zrow[w][l4 * 64];
    for (int ci = 0; ci < nchunk; ++ci) {
      int k;
      if (doEx) k = ci * 16 + c16p;
      else      k = glist[w][ci >> 1] * 32 + (ci & 1) * 16 + c16p;
      const float* erow = emb + (size_t)k * DDIM + l4 * 64;   // lane's 64-dim slice
      double s0 = 0.0, s1 = 0.0;
      #pragma unroll
      for (int jj = 0; jj < 8; ++jj) {
        const float4 e0 = *(const float4*)(erow + jj * 8);
        const float4 z0 = *(const float4*)(zp4 + jj * 8);
        const float4 e1 = *(const float4*)(erow + jj * 8 + 4);
        const float4 z1 = *(const float4*)(zp4 + jj * 8 + 4);
        s0 += (double)z0.x * (double)e0.x + (double)z0.y * (double)e0.y
            + (double)z0.z * (double)e0.z + (double)z0.w * (double)e0.w;
        s1 += (double)z1.x * (double)e1.x + (double)z1.y * (double)e1.y
            + (double)z1.z * (double)e1.z + (double)z1.w * (double)e1.w;
      }
      double s = s0 + s1;
      s += __shfl_xor(s, 1, 4);
      s += __shfl_xor(s, 2, 4);         // full 256-dim fp64 dot at l4==0
      if (l4 == 0) {
        const float mm = (float)s;                   // exact dot -> one fp32 rounding
        const float d = (zzn + ee[k]) - 2.0f * mm;   // replicate ref quantization (d > 0)
        const ull c = ((ull)__float_as_uint(d) << 32) | (unsigned int)k;
        if (c < best) best = c;                      // lexicographic (d, k): first idx wins
      }
    }
    // fold the 16 l4==0 leaders (xor group {4,8,16,32})
    ull b0 = best;
    #pragma unroll
    for (int o = 4; o <= 32; o <<= 1) {
      const ull ot = __shfl_xor(b0, o, 64);
      b0 = ot < b0 ? ot : b0;
    }
    if (lane == 0) {
      const int k0 = (int)(b0 & 0xffffffffu);
      idx[n] = k0;
      out_idxf[n] = (float)k0;
      atomicAdd(&counts[k0], 1);
      dsum += (double)__uint_as_float((unsigned int)(b0 >> 32));  // winner d = sum((zq-z)^2)
    }
  }
  if (lane == 0) wsum[w] = dsum;
  __syncthreads();
  if (tid == 0) lsum[blockIdx.x] = wsum[0] + wsum[1] + wsum[2] + wsum[3];
}

// ---------------- scatter z_q: pure gather + coalesced NCHW write (R13) ----------------
__global__ __launch_bounds__(256) void k_scatter(
    const float* __restrict__ emb, const int* __restrict__ idx,
    float* __restrict__ out_zq) {
  __shared__ float et[64][257];   // 64 tokens x 256 dims, pad 257
  __shared__ int sidx[64];
  const int tg = blockIdx.x;      // 256 groups of 64 tokens
  const int n0 = tg * 64;
  const int b = n0 >> 10, hw0 = n0 & 1023;
  const int tid = threadIdx.x;
  if (tid < 64) sidx[tid] = idx[n0 + tid];
  __syncthreads();
  for (int i = tid; i < 16384; i += 256) {      // gather code rows (coalesced along d)
    const int t = i >> 8, d = i & 255;
    et[t][d] = emb[(size_t)sidx[t] * DDIM + d];
  }
  __syncthreads();
  float* ob = out_zq + (size_t)b * CHW + hw0;
  for (int i = tid; i < 16384; i += 256) {      // NCHW order: coalesced zq writes
    const int d = i >> 6, t = i & 63;
    ob[(size_t)d * HWD + t] = et[t][d];         // z_q_st == z_q numerically
  }
}

// ---------------- entropy + loss finals (single block, R13) ----------------
__global__ __launch_bounds__(256) void k_histfinal(const int* __restrict__ counts,
                                                   const double* __restrict__ lsum,
                                                   float* __restrict__ out_loss,
                                                   float* __restrict__ out_perp) {
  __shared__ double w4[4], l4a[4];
  const int tid = threadIdx.x;
  double s = 0.0, l = 0.0;
  for (int i = tid; i < 16384; i += 256) {
    const float em = (float)counts[i] * (1.0f / 16384.0f);
    s += (double)(em * logf(em + 1e-10f));
  }
  for (int i = tid; i < 2048; i += 256) l += lsum[i];
  #pragma unroll
  for (int o = 32; o; o >>= 1) {
    s += __shfl_xor(s, o, 64);
    l += __shfl_xor(l, o, 64);
  }
  const int wid = tid >> 6, lane = tid & 63;
  if (lane == 0) { w4[wid] = s; l4a[wid] = l; }
  __syncthreads();
  if (tid == 0) {
    const double S = w4[0] + w4[1] + w4[2] + w4[3];
    const double L = l4a[0] + l4a[1] + l4a[2] + l4a[3];
    out_loss[0] = (float)(1.25 * L / 4194304.0);  // (1+BETA)*mean
    out_perp[0] = (float)exp(-S);
  }
}

extern "C" void kernel_launch(void* const* d_in, const int* in_sizes, int n_in,
                              void* d_out, int out_size, void* d_ws, size_t ws_size,
                              hipStream_t stream) {
  const float* z   = (const float*)d_in[0];   // [16,256,32,32]
  const float* emb = (const float*)d_in[1];   // [16384,256]
  float* out      = (float*)d_out;
  float* out_zq   = out;                      // 4194304
  float* out_loss = out + 4194304;
  float* out_perp = out + 4194305;
  float* out_idxf = out + 4194306;            // 16384 (idx as float)
  float* zt       = out;                      // [n][d] fp32; dead before k_scatter overwrites

  char* ws = (char*)d_ws;
  char* Ti8 = ws + WS_TI8;
  char* Ci8 = ws + WS_CI8;
  _Float16* M3 = (_Float16*)(ws + WS_M3);
  unsigned char* flags = (unsigned char*)(ws + WS_FLG);
  float*  ee      = (float*)(ws + WS_EE);
  float*  zz      = (float*)(ws + WS_ZZ);
  int*    idx     = (int*)  (ws + WS_IDX);
  int*    counts  = (int*)  (ws + WS_CNT);
  double* lsum    = (double*)(ws + WS_LSUM);

  hipMemsetAsync(counts, 0, 65536, stream);

  k_prep <<<512, 256, 0, stream>>>(z, emb, Ti8, Ci8, zz, ee, zt, flags);
  k_mdist<<<2048, 256, 0, stream>>>(Ti8, Ci8, M3);
  k_pick <<<2048, 256, 0, stream>>>(zt, emb, zz, ee, M3, flags,
                                    idx, out_idxf, counts, lsum);
  k_scatter<<<256, 256, 0, stream>>>(emb, idx, out_zq);
  k_histfinal<<<1, 256, 0, stream>>>(counts, lsum, out_loss, out_perp);
}